// Round 3
// baseline (59.466 us; speedup 1.0000x reference)
//
#include <hip/hip_runtime.h>

// Grouped width-conv (2 groups x 12ch, k=7, same-pad, shared weights) + roll(+1,h).
// x: (1,24,112,112) f32, W: (12,12,7) f32 as W[i][oc][j]; out f32 (1,24,112,112).
// v3: NO LDS, NO barrier. One thread per 4 consecutive w outputs.
//   - 75264 threads = 294 blocks x 256. tid -> (c_out, h, w4).
//   - c_out = tid/3136 is wave-uniform (3136 = 49*64), so weight loads are
//     forced scalar via readfirstlane -> s_load broadcast, zero vector cost.
//   - x rows read directly from global (1.2 MB, L2-resident): 3 aligned float4
//     per input channel (sliding window w4-4 .. w4+7), edges predicated to zero.
//   - No sync point anywhere: loads pipeline freely, no vmcnt(0)+barrier drain.

__global__ __launch_bounds__(256) void shiftconv_kernel(
    const float* __restrict__ x, const float* __restrict__ W, float* __restrict__ out)
{
    const int tid = blockIdx.x * 256 + threadIdx.x;     // 0..75263
    const int c   = tid / 3136;                         // 0..23, wave-uniform
    const int rem = tid - c * 3136;
    const int h   = rem / 28;                           // 0..111
    const int w4  = (rem - h * 28) * 4;                 // 0,4,...,108
    const int g   = c / 12;
    const int oc  = __builtin_amdgcn_readfirstlane(c - g * 12);  // scalar 0..11
    const int h_src = (h + 111) % 112;                  // roll(+1): out h <- src h-1

    const float* xrow0 = x + (g * 12 * 112 + h_src) * 112;   // + i*12544 + col

    float acc0 = 0.f, acc1 = 0.f, acc2 = 0.f, acc3 = 0.f;

    #pragma unroll
    for (int i = 0; i < 12; ++i) {
        const float* row = xrow0 + i * 12544;
        float4 xa = make_float4(0.f, 0.f, 0.f, 0.f);
        float4 xc = make_float4(0.f, 0.f, 0.f, 0.f);
        if (w4 > 0)   xa = *reinterpret_cast<const float4*>(row + w4 - 4);
        const float4 xb = *reinterpret_cast<const float4*>(row + w4);
        if (w4 < 108) xc = *reinterpret_cast<const float4*>(row + w4 + 4);
        // xv[p] = x at column w4 - 4 + p; need w = w4 + m + j - 3 -> p = m + j + 1
        const float xv[12] = {xa.x, xa.y, xa.z, xa.w,
                              xb.x, xb.y, xb.z, xb.w,
                              xc.x, xc.y, xc.z, xc.w};
        const int wb = (i * 12 + oc) * 7;               // scalar offset
        #pragma unroll
        for (int j = 0; j < 7; ++j) {
            const float wj = W[wb + j];                 // s_load broadcast
            acc0 += xv[j + 1] * wj;
            acc1 += xv[j + 2] * wj;
            acc2 += xv[j + 3] * wj;
            acc3 += xv[j + 4] * wj;
        }
    }

    *reinterpret_cast<float4*>(out + (c * 112 + h) * 112 + w4) =
        make_float4(acc0, acc1, acc2, acc3);
}

extern "C" void kernel_launch(void* const* d_in, const int* in_sizes, int n_in,
                              void* d_out, int out_size, void* d_ws, size_t ws_size,
                              hipStream_t stream) {
    const float* x = (const float*)d_in[0];
    const float* W = (const float*)d_in[1];
    float* out     = (float*)d_out;
    shiftconv_kernel<<<294, 256, 0, stream>>>(x, W, out);
}